// Round 10
// baseline (260.313 us; speedup 1.0000x reference)
//
#include <hip/hip_runtime.h>
#include <hip/hip_bf16.h>

// Problem constants (from reference)
#define TT 128   // time points
#define DD 64    // state dim
#define HH 256   // f-net hidden
#define HK 128   // kernel-net hidden
#define JH (TT*HK)      // 16384 contraction dim
#define HD (HK*DD)      // 8192
#define NCHUNK 16       // jh chunks of 1024 (= 8 j's each)
#define CW 1024         // chunk width in jh

// ---------------------------------------------------------------------------
// k_F0 (it=0 only): block j: y = z0, F[j] = tanh(y@W1+b1)@W2+b2,
// bF[j,d] = sum_e bk2[d*DD+e]*F[j,e]
// ---------------------------------------------------------------------------
__global__ void __launch_bounds__(256)
k_F0(const float* __restrict__ z0,
     const float* __restrict__ W1, const float* __restrict__ b1,
     const float* __restrict__ W2, const float* __restrict__ b2,
     const float* __restrict__ bk2,
     float* __restrict__ F, float* __restrict__ bF) {
    int j = blockIdx.x, tid = threadIdx.x;
    int part = tid >> 6, d = tid & 63;
    __shared__ float red[4][64];
    __shared__ float ys[DD];
    __shared__ float hs[HH];
    __shared__ float fs[DD];
    if (tid < DD) ys[tid] = z0[tid];
    __syncthreads();
    float acc = b1[tid];
    #pragma unroll 8
    for (int e = 0; e < DD; ++e) acc += ys[e] * W1[e * HH + tid];
    hs[tid] = tanhf(acc);
    __syncthreads();
    {
        float s = 0.f;
        #pragma unroll 8
        for (int h = part * 64; h < part * 64 + 64; ++h) s += hs[h] * W2[h * DD + d];
        red[part][d] = s;
    }
    __syncthreads();
    if (part == 0) {
        float a = b2[d] + red[0][d] + red[1][d] + red[2][d] + red[3][d];
        fs[d] = a;
        F[j * DD + d] = a;
    }
    __syncthreads();
    {
        float s = 0.f;
        #pragma unroll
        for (int e = part * 16; e < part * 16 + 16; ++e) s += bk2[d * DD + e] * fs[e];
        red[part][d] = s;
    }
    __syncthreads();
    if (part == 0)
        bF[j * DD + d] = red[0][d] + red[1][d] + red[2][d] + red[3][d];
}

// ---------------------------------------------------------------------------
// k_FP (it>0): block j reconstructs y_j DIRECTLY from P partials + bF_prev
// (no G buffer, no Gfin launch):
//   G[p,d] = sum_{c<=p>>3} P[c,p,d] + bFt[p,d]
//   y_j = z0 + dt * sum_{1<=p<=j} w_jp G[p,d]     (G[0] == 0 exactly)
// bFt handled by a serial LDS scan; P-sum by a batched 8-deep L2 loop.
// Then the standard MLP -> F[j], bF_cur[j].
// ---------------------------------------------------------------------------
__global__ void __launch_bounds__(256)
k_FP(const float* __restrict__ P, const float* __restrict__ bFin,
     const float* __restrict__ z0, const float* __restrict__ t,
     const float* __restrict__ W1, const float* __restrict__ b1,
     const float* __restrict__ W2, const float* __restrict__ b2,
     const float* __restrict__ bk2,
     float* __restrict__ F, float* __restrict__ bFout) {
    int j = blockIdx.x, tid = threadIdx.x;
    int part = tid >> 6, d = tid & 63;
    __shared__ float bfs[TT][DD];      // 32 KB (rows 0..j used)
    __shared__ float red[4][64];
    __shared__ float ys[DD];
    __shared__ float hs[HH];
    __shared__ float fs[DD];
    float dt = t[1] - t[0];

    // stage bF_prev rows 0..j
    for (int k = tid; k < (j + 1) * DD; k += 256) bfs[k >> 6][k & 63] = bFin[k];

    // B-part: s1 = sum_{1<=p<=j} w_jp * sum_c P[c,p,d], p strided over part
    float s1 = 0.f;
    for (int p = part; p <= j; p += 4) {
        if (p == 0) continue;
        int cmax = p >> 3;
        float a = 0.f;
        int c = 0;
        for (; c + 7 <= cmax; c += 8) {
            float p0 = P[(size_t)(c + 0) * (TT * DD) + p * DD + d];
            float p1 = P[(size_t)(c + 1) * (TT * DD) + p * DD + d];
            float p2 = P[(size_t)(c + 2) * (TT * DD) + p * DD + d];
            float p3 = P[(size_t)(c + 3) * (TT * DD) + p * DD + d];
            float p4 = P[(size_t)(c + 4) * (TT * DD) + p * DD + d];
            float p5 = P[(size_t)(c + 5) * (TT * DD) + p * DD + d];
            float p6 = P[(size_t)(c + 6) * (TT * DD) + p * DD + d];
            float p7 = P[(size_t)(c + 7) * (TT * DD) + p * DD + d];
            a += ((p0 + p1) + (p2 + p3)) + ((p4 + p5) + (p6 + p7));
        }
        for (; c <= cmax; ++c) a += P[(size_t)c * (TT * DD) + p * DD + d];
        float wp = (p == j) ? 0.5f : 1.0f;
        s1 += wp * a;
    }
    red[part][d] = s1;
    __syncthreads();

    if (part == 0) {
        // bFt-part: serial scan over LDS-resident bF_prev
        //   bFt[p] = dt*(S_{p-1} - 0.5*B0 + 0.5*Bp), S_k = sum_{q<=k} Bq
        float sT = 0.f;
        if (j > 0) {
            float B0 = bfs[0][d];
            float S = B0;
            for (int p = 1; p <= j; ++p) {
                float Bp = bfs[p][d];
                float bft = dt * (S - 0.5f * B0 + 0.5f * Bp);
                float wp = (p == j) ? 0.5f : 1.0f;
                sT += wp * bft;
                S += Bp;
            }
        }
        float Bsum = red[0][d] + red[1][d] + red[2][d] + red[3][d];
        ys[d] = z0[d] + dt * (Bsum + sT);
    }
    __syncthreads();

    // ---- standard MLP ----
    float acc = b1[tid];
    #pragma unroll 8
    for (int e = 0; e < DD; ++e) acc += ys[e] * W1[e * HH + tid];
    hs[tid] = tanhf(acc);
    __syncthreads();
    {
        float s = 0.f;
        #pragma unroll 8
        for (int h = part * 64; h < part * 64 + 64; ++h) s += hs[h] * W2[h * DD + d];
        red[part][d] = s;
    }
    __syncthreads();
    if (part == 0) {
        float a = b2[d] + red[0][d] + red[1][d] + red[2][d] + red[3][d];
        fs[d] = a;
        F[j * DD + d] = a;
    }
    __syncthreads();
    {
        float s = 0.f;
        #pragma unroll
        for (int e = part * 16; e < part * 16 + 16; ++e) s += bk2[d * DD + e] * fs[e];
        red[part][d] = s;
    }
    __syncthreads();
    if (part == 0)
        bFout[j * DD + d] = red[0][d] + red[1][d] + red[2][d] + red[3][d];
}

// ---------------------------------------------------------------------------
// k_M (r9-proven): M[j*HD + hd] = sum_e F[j,e] * Wk2[h, d*DD + e]
// grid: (32 hd-chunks of 256, 16 j-chunks of 8)
// ---------------------------------------------------------------------------
__global__ void __launch_bounds__(256)
k_M(const float* __restrict__ F, const float* __restrict__ Wk2,
    float* __restrict__ M) {
    int tid = threadIdx.x;
    int hd = blockIdx.x * 256 + tid;
    int j0 = blockIdx.y * 8;
    __shared__ __attribute__((aligned(16))) float Fs[8][64];
    for (int k = tid; k < 8 * DD; k += 256) Fs[k >> 6][k & 63] = F[j0 * DD + k];
    __syncthreads();
    float acc[8] = {0.f,0.f,0.f,0.f,0.f,0.f,0.f,0.f};
    const float* Wrow = Wk2 + (size_t)(hd >> 6) * (DD * DD) + (size_t)(hd & 63) * DD;
    for (int e = 0; e < DD; e += 8) {
        float4 wa = *(const float4*)(Wrow + e);
        float4 wb = *(const float4*)(Wrow + e + 4);
        #pragma unroll
        for (int r = 0; r < 8; ++r) {
            float4 f0 = *(const float4*)&Fs[r][e];
            float4 f1 = *(const float4*)&Fs[r][e + 4];
            acc[r] += f0.x*wa.x + f0.y*wa.y + f0.z*wa.z + f0.w*wa.w
                    + f1.x*wb.x + f1.y*wb.y + f1.z*wb.z + f1.w*wb.w;
        }
    }
    #pragma unroll
    for (int r = 0; r < 8; ++r) M[(size_t)(j0 + r) * HD + hd] = acc[r];
}

// ---------------------------------------------------------------------------
// k_G1: wide chunks (1024 jh = 8 j). P[c,i,d] = sum_{jh in chunk} A[i,jh]*M[jh,d]
// grid (16 itiles, 16 chunks); active iff c <= itile (136 blocks).
// A computed on the fly (32 tanh/thread). Final iteration: block (0,0)
// seeds out = z0 for k_out2's atomics.
// ---------------------------------------------------------------------------
__global__ void __launch_bounds__(256)
k_G1(const float* __restrict__ t, const float* __restrict__ Wk1,
     const float* __restrict__ bk1, const float* __restrict__ M,
     float* __restrict__ P, const float* __restrict__ z0,
     float* __restrict__ out, int final_it) {
    int itile = blockIdx.x, c = blockIdx.y;
    if (c > itile) return;
    __shared__ __attribute__((aligned(16))) float As[8 * CW];    // 32 KB
    __shared__ float red[4][8][64];                              // 8 KB
    int tid = threadIdx.x, sub = tid >> 6, d = tid & 63;

    // ---- on-the-fly A tile: thread covers h = tid&127, jloc = 2*jj+(tid>>7) ----
    {
        float dt = t[1] - t[0];
        int h = tid & 127, jhi = tid >> 7;
        float wk0 = Wk1[h], wk1v = Wk1[HK + h], bk = bk1[h];
        float ti[8];
        #pragma unroll
        for (int k = 0; k < 8; ++k) ti[k] = t[itile * 8 + k];
        #pragma unroll
        for (int jj = 0; jj < 4; ++jj) {
            int jloc = jj * 2 + jhi;
            int j = c * 8 + jloc;
            float tj = t[j];
            #pragma unroll
            for (int k = 0; k < 8; ++k) {
                int i = itile * 8 + k;
                float w = (i == 0 || j > i) ? 0.f : dt * ((j == 0 || j == i) ? 0.5f : 1.0f);
                As[k * CW + jloc * HK + h] = w * tanhf(ti[k] * wk0 + tj * wk1v + bk);
            }
        }
    }
    if (final_it && itile == 0 && c == 0 && tid < DD) out[tid] = z0[tid];
    __syncthreads();

    float acc[8] = {0.f,0.f,0.f,0.f,0.f,0.f,0.f,0.f};
    const float* Mp = M + ((size_t)c * CW) * DD + d;
    int jl0 = sub * 256;
    for (int jl = jl0; jl < jl0 + 256; jl += 8) {
        float m0 = Mp[(size_t)(jl + 0) * DD];
        float m1 = Mp[(size_t)(jl + 1) * DD];
        float m2 = Mp[(size_t)(jl + 2) * DD];
        float m3 = Mp[(size_t)(jl + 3) * DD];
        float m4 = Mp[(size_t)(jl + 4) * DD];
        float m5 = Mp[(size_t)(jl + 5) * DD];
        float m6 = Mp[(size_t)(jl + 6) * DD];
        float m7 = Mp[(size_t)(jl + 7) * DD];
        #pragma unroll
        for (int r = 0; r < 8; ++r) {
            float4 a0 = *(const float4*)&As[r * CW + jl];
            float4 a1 = *(const float4*)&As[r * CW + jl + 4];
            acc[r] += a0.x*m0 + a0.y*m1 + a0.z*m2 + a0.w*m3
                    + a1.x*m4 + a1.y*m5 + a1.z*m6 + a1.w*m7;
        }
    }
    #pragma unroll
    for (int r = 0; r < 8; ++r) red[sub][r][d] = acc[r];
    __syncthreads();
    if (sub == 0) {
        #pragma unroll
        for (int r = 0; r < 8; ++r) {
            float v = red[0][r][d] + red[1][r][d] + red[2][r][d] + red[3][r][d];
            P[(size_t)c * (TT * DD) + (itile * 8 + r) * DD + d] = v;
        }
    }
}

// ---------------------------------------------------------------------------
// k_out2: block j computes G[j,d] from P + bF and atomicAdds dt*w_j*G[j,d]
// into out (pre-seeded = z0 by the final k_G1). 8K atomics over 64 addresses.
// ---------------------------------------------------------------------------
__global__ void __launch_bounds__(256)
k_out2(const float* __restrict__ P, const float* __restrict__ bF,
       const float* __restrict__ t, float* __restrict__ out) {
    int j = blockIdx.x, tid = threadIdx.x;
    int part = tid >> 6, d = tid & 63;
    __shared__ float red[4][64];
    float dt = t[1] - t[0];
    float a = 0.f;
    int cmax = j >> 3;
    for (int c = part; c <= cmax; c += 4) a += P[(size_t)c * (TT * DD) + j * DD + d];
    if (j > 0) {
        float s = 0.f;
        for (int jp = part; jp <= j; jp += 4) {
            float w = (jp == 0 || jp == j) ? 0.5f : 1.0f;
            s += w * bF[jp * DD + d];
        }
        a += dt * s;
    }
    red[part][d] = a;
    __syncthreads();
    if (part == 0) {
        float v = red[0][d] + red[1][d] + red[2][d] + red[3][d];
        float wj = (j == 0 || j == TT - 1) ? 0.5f : 1.0f;
        atomicAdd(&out[d], dt * wj * v);
    }
}

extern "C" void kernel_launch(void* const* d_in, const int* in_sizes, int n_in,
                              void* d_out, int out_size, void* d_ws, size_t ws_size,
                              hipStream_t stream) {
    const float* z0  = (const float*)d_in[0];
    const float* t   = (const float*)d_in[1];
    const float* W1  = (const float*)d_in[2];
    const float* b1  = (const float*)d_in[3];
    const float* W2  = (const float*)d_in[4];
    const float* b2  = (const float*)d_in[5];
    const float* Wk1 = (const float*)d_in[6];
    const float* bk1 = (const float*)d_in[7];
    const float* Wk2 = (const float*)d_in[8];
    const float* bk2 = (const float*)d_in[9];
    float* out = (float*)d_out;

    float* ws  = (float*)d_ws;
    float* M   = ws;                        // T*HK*D     = 1,048,576
    float* F   = M   + (size_t)TT*HK*DD;    // T*D
    float* bFA = F   + TT*DD;               // T*D
    float* bFB = bFA + TT*DD;               // T*D
    float* P   = bFB + TT*DD;               // NCHUNK*T*D = 131,072

    // 10 launches:
    // it0: F0 -> M -> G1
    k_F0<<<TT, 256, 0, stream>>>(z0, W1, b1, W2, b2, bk2, F, bFA);
    k_M<<<dim3(32, 16), 256, 0, stream>>>(F, Wk2, M);
    k_G1<<<dim3(16, NCHUNK), 256, 0, stream>>>(t, Wk1, bk1, M, P, z0, out, 0);
    // it1: FP(P,bFA->bFB) -> M -> G1
    k_FP<<<TT, 256, 0, stream>>>(P, bFA, z0, t, W1, b1, W2, b2, bk2, F, bFB);
    k_M<<<dim3(32, 16), 256, 0, stream>>>(F, Wk2, M);
    k_G1<<<dim3(16, NCHUNK), 256, 0, stream>>>(t, Wk1, bk1, M, P, z0, out, 0);
    // it2: FP(P,bFB->bFA) -> M -> G1(seed out) -> out2
    k_FP<<<TT, 256, 0, stream>>>(P, bFB, z0, t, W1, b1, W2, b2, bk2, F, bFA);
    k_M<<<dim3(32, 16), 256, 0, stream>>>(F, Wk2, M);
    k_G1<<<dim3(16, NCHUNK), 256, 0, stream>>>(t, Wk1, bk1, M, P, z0, out, 1);
    k_out2<<<TT, 256, 0, stream>>>(P, bFA, t, out);
}